// Round 15
// baseline (149.636 us; speedup 1.0000x reference)
//
#include <hip/hip_runtime.h>
#include <hip/hip_bf16.h>

#define BATCH  512
#define IN_F   4096
#define OUT_F  4096
#define CAP    208     // bucket capacity; Poisson(122), overflow prob ~1e-11/row
#define CSTR   16      // counts stride (ints): 1 counter per 64-B line (atomic contention fix)

typedef __attribute__((ext_vector_type(8))) short bf16x8;   // 8 bf16 = 4 VGPR (MFMA A/B frag)
typedef __attribute__((ext_vector_type(4))) float f32x4;    // MFMA C/D frag

// bf16 round-to-nearest-even bits from fp32
__device__ __forceinline__ unsigned bf16_bits(float f) {
    unsigned u = __float_as_uint(f);
    return (u + 0x7FFFu + ((u >> 16) & 1u)) >> 16;
}
__device__ __forceinline__ float bf16_val(unsigned bits16) {
    return __uint_as_float(bits16 << 16);
}

// ---------------- 0) convert x fp32 -> bf16  +  zero counts  +  zero tickets ----------------
__global__ void convert_cnt_kernel(const float* __restrict__ x, __hip_bfloat16* __restrict__ xb,
                                   int* __restrict__ counts, int* __restrict__ tickets) {
    const int NC = BATCH * IN_F / 4;      // x convert threads (float4 each)
    int i = blockIdx.x * blockDim.x + threadIdx.x;
    if (i < NC) {
        float4 v = ((const float4*)x)[i];
        unsigned lo = bf16_bits(v.x) | (bf16_bits(v.y) << 16);
        unsigned hi = bf16_bits(v.z) | (bf16_bits(v.w) << 16);
        ((uint2*)xb)[i] = make_uint2(lo, hi);
    } else if (i < NC + OUT_F) {
        counts[(i - NC) * CSTR] = 0;                      // one counter per line
    } else if (i < NC + OUT_F + 32) {
        tickets[i - NC - OUT_F] = 0;                      // gemm completion tickets
    }
}

// ---------------- 1) scatter entries into fixed-capacity row buckets ----------------
// packed[r*CAP + k] = (bf16(w) << 16) | col   (col fits 12 bits)
__global__ void scatter_pairs_kernel(const int* __restrict__ rows,
                                     const int* __restrict__ cols,
                                     const float* __restrict__ w,
                                     int nnz,
                                     int* __restrict__ counts,
                                     unsigned* __restrict__ pairs) {
    int i = blockIdx.x * blockDim.x + threadIdx.x;
    int i4 = i * 4;
    if (i4 + 4 <= nnz) {
        int4   r  = ((const int4*)rows)[i];
        int4   c  = ((const int4*)cols)[i];
        float4 wv = ((const float4*)w)[i];
        int p0 = atomicAdd(&counts[r.x * CSTR], 1);
        if (p0 < CAP) pairs[(size_t)r.x * CAP + p0] = (bf16_bits(wv.x) << 16) | (unsigned)c.x;
        int p1 = atomicAdd(&counts[r.y * CSTR], 1);
        if (p1 < CAP) pairs[(size_t)r.y * CAP + p1] = (bf16_bits(wv.y) << 16) | (unsigned)c.y;
        int p2 = atomicAdd(&counts[r.z * CSTR], 1);
        if (p2 < CAP) pairs[(size_t)r.z * CAP + p2] = (bf16_bits(wv.z) << 16) | (unsigned)c.z;
        int p3 = atomicAdd(&counts[r.w * CSTR], 1);
        if (p3 < CAP) pairs[(size_t)r.w * CAP + p3] = (bf16_bits(wv.w) << 16) | (unsigned)c.w;
    } else {
        for (int j = i4; j < nnz; ++j) {
            int rr = rows[j];
            int pp = atomicAdd(&counts[rr * CSTR], 1);
            if (pp < CAP) pairs[(size_t)rr * CAP + pp] = (bf16_bits(w[j]) << 16) | (unsigned)cols[j];
        }
    }
}

// ---------------- 2) densify: one block per output row -> bf16 dense W (N,K) ----------------
__global__ __launch_bounds__(256) void densify_rows_kernel(const unsigned* __restrict__ pairs,
                                                           const int* __restrict__ counts,
                                                           __hip_bfloat16* __restrict__ Wb) {
    __shared__ __align__(16) float row[IN_F];   // 16 KB
    const int r = blockIdx.x;
    const int t = threadIdx.x;
    const float4 z = make_float4(0.f, 0.f, 0.f, 0.f);
#pragma unroll
    for (int k = 0; k < IN_F / 4 / 256; ++k)
        ((float4*)row)[t + k * 256] = z;
    __syncthreads();
    int cnt = counts[r * CSTR];
    if (cnt > CAP) cnt = CAP;
    const unsigned* bucket = pairs + (size_t)r * CAP;
    for (int j = t; j < cnt; j += 256) {
        unsigned p = bucket[j];
        atomicAdd(&row[p & 0xFFFu], __uint_as_float(p & 0xFFFF0000u));
    }
    __syncthreads();
    unsigned* dst = (unsigned*)(Wb + (size_t)r * IN_F);
#pragma unroll
    for (int k = 0; k < (IN_F / 2) / 256; ++k) {
        int ui = t + k * 256;
        unsigned lo = bf16_bits(row[ui * 2]);
        unsigned hi = bf16_bits(row[ui * 2 + 1]);
        dst[ui] = lo | (hi << 16);
    }
}

// ---------------- 3) GEMM + fused reduction ----------------
// K-loop byte-identical to rounds 12/14 (256^2 tile, BK=64, 8 waves 2Mx4N, counted
// vmcnt(8), pre-swizzled row-major LDS). XCD-paired mapping (R14): all 16 blocks
// (2m x 8ksp) of an n-band live on one XCD. NEW: after streaming its bf16 partial,
// each block tickets tickets[g]; the 8th finisher for tile g=(m,n) reduces the 8
// partial slices (L2-hot, just written on the same XCD) + bias -> out. Kills the
// separate reduce kernel and its cold 32 MB HBM re-read.
#define BM  256
#define BN  256
#define BKT 64
#define KSPLIT 8
#define KH   (IN_F / KSPLIT)            // 512
#define NKTH (KH / BKT)                 // 8
#define NWG  ((BATCH / BM) * (OUT_F / BN) * KSPLIT)   // 256

__global__ __launch_bounds__(512, 1) void gemm_fused_kernel(
    const __hip_bfloat16* __restrict__ xb,   // (512, 4096) row-major
    const __hip_bfloat16* __restrict__ Wb,   // (4096, 4096) = (N, K) row-major
    unsigned* __restrict__ parts,            // KSPLIT x (256, 4096) uint (2 bf16 rows each)
    const float* __restrict__ bias,
    float* __restrict__ out,                 // (512, 4096) fp32
    int* __restrict__ tickets) {             // 32 ints, zeroed by kernel 0

    __shared__ __align__(16) __hip_bfloat16 As[2][BM][BKT];   // 64 KB
    __shared__ __align__(16) __hip_bfloat16 Bs[2][BN][BKT];   // 64 KB

    // XCD-paired decomposition (xcd heuristic: bid % 8)
    const int xcd = blockIdx.x & 7;
    const int r   = blockIdx.x >> 3;          // 0..31
    const int bn0 = (2 * xcd + (r & 1)) * BN; // n tile 0..15
    const int bm0 = ((r >> 1) & 1) * BM;      // m tile 0..1
    const int ksp = r >> 2;                   // 0..7
    const size_t k0 = (size_t)ksp * KH;

    const int t  = threadIdx.x;               // 0..511
    const int l  = t & 63;
    const int w  = t >> 6;                    // wave 0..7
    const int wr = w >> 2;                    // M-half 0..1 (128 rows)
    const int wc = w & 3;                     // N-quarter 0..3 (64 cols)
    const int lr = l & 15;                    // frag lane
    const int lg = l >> 4;                    // k-group 0..3

    f32x4 acc[8][4] = {};

#define STAGE(p, kt) do {                                                                         \
    _Pragma("unroll")                                                                             \
    for (int j = 0; j < 4; ++j) {                                                                 \
        int q = t + j * 512; int row = q >> 3; int kcg = (q & 7) ^ (row & 7);                     \
        __builtin_amdgcn_global_load_lds(                                                         \
            (const unsigned*)(xb + (size_t)(bm0 + row) * IN_F + k0 + (kt) * BKT + kcg * 8),       \
            (unsigned*)((__hip_bfloat16*)As[p] + q * 8), 16, 0, 0);                               \
    }                                                                                             \
    _Pragma("unroll")                                                                             \
    for (int j = 0; j < 4; ++j) {                                                                 \
        int q = t + j * 512; int row = q >> 3; int kcg = (q & 7) ^ (row & 7);                     \
        __builtin_amdgcn_global_load_lds(                                                         \
            (const unsigned*)(Wb + (size_t)(bn0 + row) * IN_F + k0 + (kt) * BKT + kcg * 8),       \
            (unsigned*)((__hip_bfloat16*)Bs[p] + q * 8), 16, 0, 0);                               \
    }                                                                                             \
} while (0)

    const int rowA0 = wr * 128 + lr;          // +16i ; (row&7) == (lr&7) for all i
    const int rowB0 = wc * 64 + lr;
    const int xA = lr & 7;
    const int xB = lr & 7;

    STAGE(0, 0);
    for (int kt = 0; kt < NKTH; ++kt) {
        const int p = kt & 1;
        if (kt + 1 < NKTH) {
            STAGE(p ^ 1, kt + 1);                              // 8 more loads in flight
            asm volatile("s_waitcnt vmcnt(8)" ::: "memory");   // tile kt's 8 landed
        } else {
            asm volatile("s_waitcnt vmcnt(0)" ::: "memory");   // final tile: full drain
        }
        __builtin_amdgcn_s_barrier();                          // all waves: tile kt ready

#pragma unroll
        for (int ks = 0; ks < 2; ++ks) {
            const int kc = ks * 4 + lg;
            bf16x8 a[8], b[4];
#pragma unroll
            for (int i = 0; i < 8; ++i)
                a[i] = *(const bf16x8*)&As[p][rowA0 + 16 * i][(kc ^ xA) * 8];
#pragma unroll
            for (int i = 0; i < 4; ++i)
                b[i] = *(const bf16x8*)&Bs[p][rowB0 + 16 * i][(kc ^ xB) * 8];
#pragma unroll
            for (int i = 0; i < 8; ++i)
#pragma unroll
                for (int j = 0; j < 4; ++j)
                    acc[i][j] = __builtin_amdgcn_mfma_f32_16x16x32_bf16(a[i], b[j], acc[i][j], 0, 0, 0);
        }
        __builtin_amdgcn_s_barrier();   // all waves done reading buf p before restage
    }

    // epilogue: pack row-pairs (rows 2r, 2r+1) as 2xbf16 in one uint; stream (no atomics).
    unsigned* pout = parts + (size_t)ksp * (BATCH / 2) * OUT_F;
    const int col  = bn0 + wc * 64 + lr;
    const int row0 = bm0 + wr * 128 + lg * 4;
#pragma unroll
    for (int i = 0; i < 8; ++i) {
        const int rp = (row0 + i * 16) >> 1;    // row-pair index
#pragma unroll
        for (int j = 0; j < 4; ++j) {
            unsigned u0 = bf16_bits(acc[i][j][0]) | (bf16_bits(acc[i][j][1]) << 16);
            unsigned u1 = bf16_bits(acc[i][j][2]) | (bf16_bits(acc[i][j][3]) << 16);
            pout[(size_t)rp * OUT_F + col + j * 16]       = u0;
            pout[(size_t)(rp + 1) * OUT_F + col + j * 16] = u1;
        }
    }

    // ---- fused reduction: 8th finisher of tile g reduces all KSPLIT partials + bias ----
    __threadfence();                                  // release: partial stores visible
    volatile int* flag = (volatile int*)&As[0][0][0]; // reuse dead LDS
    if (t == 0) {
        const int g = ((bm0 >> 8) << 4) | (bn0 >> 8); // 0..31
        int old = atomicAdd(&tickets[g], 1);
        *flag = (old == KSPLIT - 1) ? 1 : 0;
    }
    __syncthreads();
    if (*flag == 0) return;
    __threadfence();                                  // acquire side

    const int NPQ = (BATCH / 2) * (OUT_F / 4);        // uint4 per slice
    const uint4* pbase = (const uint4*)parts;
    const int rpBase = bm0 >> 1;
    const int cqBase = bn0 >> 2;
#pragma unroll 1
    for (int pos = t; pos < 128 * 64; pos += 512) {   // 128 row-pairs x 64 uint4-cols
        const int rpL = pos >> 6;
        const int c4  = pos & 63;
        const size_t idx = (size_t)(rpBase + rpL) * (OUT_F / 4) + cqBase + c4;
        float se0 = 0.f, se1 = 0.f, se2 = 0.f, se3 = 0.f;
        float so0 = 0.f, so1 = 0.f, so2 = 0.f, so3 = 0.f;
#pragma unroll
        for (int k = 0; k < KSPLIT; ++k) {
            uint4 v = pbase[(size_t)k * NPQ + idx];
            se0 += bf16_val(v.x & 0xFFFFu); so0 += bf16_val(v.x >> 16);
            se1 += bf16_val(v.y & 0xFFFFu); so1 += bf16_val(v.y >> 16);
            se2 += bf16_val(v.z & 0xFFFFu); so2 += bf16_val(v.z >> 16);
            se3 += bf16_val(v.w & 0xFFFFu); so3 += bf16_val(v.w >> 16);
        }
        float4 bv = ((const float4*)bias)[cqBase + c4];
        const int rowE = 2 * (rpBase + rpL);
        float4 oe = make_float4(se0 + bv.x, se1 + bv.y, se2 + bv.z, se3 + bv.w);
        float4 oo = make_float4(so0 + bv.x, so1 + bv.y, so2 + bv.z, so3 + bv.w);
        ((float4*)out)[(size_t)rowE * (OUT_F / 4) + cqBase + c4]       = oe;
        ((float4*)out)[(size_t)(rowE + 1) * (OUT_F / 4) + cqBase + c4] = oo;
    }
#undef STAGE
}

extern "C" void kernel_launch(void* const* d_in, const int* in_sizes, int n_in,
                              void* d_out, int out_size, void* d_ws, size_t ws_size,
                              hipStream_t stream) {
    const float* x    = (const float*)d_in[0];   // (512, 4096) f32
    const float* wv   = (const float*)d_in[1];   // (nnz,) f32
    const float* bias = (const float*)d_in[2];   // (4096,) f32
    const int*   idx  = (const int*)d_in[3];     // (2, nnz) int32: rows then cols
    const int nnz = in_sizes[1];
    const int* rows = idx;
    const int* cols = idx + nnz;
    float* out = (float*)d_out;

    // workspace layout (16 B aligned chunks)
    char* ws = (char*)d_ws;
    __hip_bfloat16* Wb = (__hip_bfloat16*)ws; ws += (size_t)OUT_F * IN_F * sizeof(__hip_bfloat16); // 32 MB
    __hip_bfloat16* xb = (__hip_bfloat16*)ws; ws += (size_t)BATCH * IN_F * sizeof(__hip_bfloat16); // 4 MB
    int* counts = (int*)ws;                   ws += (size_t)OUT_F * CSTR * sizeof(int);            // 256 KB
    int* tickets = (int*)ws;                  ws += 128;                                           // 32 ints
    unsigned* pairs = (unsigned*)ws;          ws += (size_t)OUT_F * CAP * sizeof(unsigned) + 256;  // ~3.4 MB
    unsigned* parts = (unsigned*)ws;          // KSPLIT * (BATCH/2) * OUT_F * 4 B = 32 MB

    // 0) x->bf16 + counts<-0 + tickets<-0
    const int NTOT = BATCH * IN_F / 4 + OUT_F + 32;
    convert_cnt_kernel<<<(NTOT + 255) / 256, 256, 0, stream>>>(x, xb, counts, tickets);

    // 1) bucket entries by row (packed 4 B: bf16 weight | col); padded counters
    int nthreads = (nnz + 3) / 4;
    int nb = (nthreads + 255) / 256;
    scatter_pairs_kernel<<<nb, 256, 0, stream>>>(rows, cols, wv, nnz, counts, pairs);

    // 2) densify W (sums duplicates via LDS atomics; writes zeros everywhere else)
    densify_rows_kernel<<<OUT_F, 256, 0, stream>>>(pairs, counts, Wb);

    // 3) dense MFMA GEMM + ticket-fused K-split reduction + bias -> out
    gemm_fused_kernel<<<NWG, 512, 0, stream>>>(xb, Wb, parts, bias, out, tickets);
}

// Round 16
// 75.457 us; speedup vs baseline: 1.9831x; 1.9831x over previous
//
#include <hip/hip_runtime.h>
#include <hip/hip_bf16.h>

#define BATCH  512
#define IN_F   4096
#define OUT_F  4096
#define CAP    208     // bucket capacity; Poisson(122), overflow prob ~1e-11/row
#define CSTR   16      // counts stride (ints): 1 counter per 64-B line (atomic contention fix)

typedef __attribute__((ext_vector_type(8))) short bf16x8;   // 8 bf16 = 4 VGPR (MFMA A/B frag)
typedef __attribute__((ext_vector_type(4))) float f32x4;    // MFMA C/D frag

// bf16 round-to-nearest-even bits from fp32
__device__ __forceinline__ unsigned bf16_bits(float f) {
    unsigned u = __float_as_uint(f);
    return (u + 0x7FFFu + ((u >> 16) & 1u)) >> 16;
}
__device__ __forceinline__ float bf16_val(unsigned bits16) {
    return __uint_as_float(bits16 << 16);
}

// ---------------- 0) convert x fp32 -> bf16  +  zero counts ----------------
__global__ void convert_cnt_kernel(const float* __restrict__ x, __hip_bfloat16* __restrict__ xb,
                                   int* __restrict__ counts) {
    const int NC = BATCH * IN_F / 4;      // x convert threads (float4 each)
    int i = blockIdx.x * blockDim.x + threadIdx.x;
    if (i < NC) {
        float4 v = ((const float4*)x)[i];
        unsigned lo = bf16_bits(v.x) | (bf16_bits(v.y) << 16);
        unsigned hi = bf16_bits(v.z) | (bf16_bits(v.w) << 16);
        ((uint2*)xb)[i] = make_uint2(lo, hi);
    } else if (i < NC + OUT_F) {
        counts[(i - NC) * CSTR] = 0;                      // one counter per line
    }
}

// ---------------- 1) scatter entries into fixed-capacity row buckets ----------------
// packed[r*CAP + k] = (bf16(w) << 16) | col   (col fits 12 bits)
__global__ void scatter_pairs_kernel(const int* __restrict__ rows,
                                     const int* __restrict__ cols,
                                     const float* __restrict__ w,
                                     int nnz,
                                     int* __restrict__ counts,
                                     unsigned* __restrict__ pairs) {
    int i = blockIdx.x * blockDim.x + threadIdx.x;
    int i4 = i * 4;
    if (i4 + 4 <= nnz) {
        int4   r  = ((const int4*)rows)[i];
        int4   c  = ((const int4*)cols)[i];
        float4 wv = ((const float4*)w)[i];
        int p0 = atomicAdd(&counts[r.x * CSTR], 1);
        if (p0 < CAP) pairs[(size_t)r.x * CAP + p0] = (bf16_bits(wv.x) << 16) | (unsigned)c.x;
        int p1 = atomicAdd(&counts[r.y * CSTR], 1);
        if (p1 < CAP) pairs[(size_t)r.y * CAP + p1] = (bf16_bits(wv.y) << 16) | (unsigned)c.y;
        int p2 = atomicAdd(&counts[r.z * CSTR], 1);
        if (p2 < CAP) pairs[(size_t)r.z * CAP + p2] = (bf16_bits(wv.z) << 16) | (unsigned)c.z;
        int p3 = atomicAdd(&counts[r.w * CSTR], 1);
        if (p3 < CAP) pairs[(size_t)r.w * CAP + p3] = (bf16_bits(wv.w) << 16) | (unsigned)c.w;
    } else {
        for (int j = i4; j < nnz; ++j) {
            int rr = rows[j];
            int pp = atomicAdd(&counts[rr * CSTR], 1);
            if (pp < CAP) pairs[(size_t)rr * CAP + pp] = (bf16_bits(w[j]) << 16) | (unsigned)cols[j];
        }
    }
}

// ---------------- 2) densify: one block per output row -> bf16 dense W (N,K) ----------------
__global__ __launch_bounds__(256) void densify_rows_kernel(const unsigned* __restrict__ pairs,
                                                           const int* __restrict__ counts,
                                                           __hip_bfloat16* __restrict__ Wb) {
    __shared__ __align__(16) float row[IN_F];   // 16 KB
    const int r = blockIdx.x;
    const int t = threadIdx.x;
    const float4 z = make_float4(0.f, 0.f, 0.f, 0.f);
#pragma unroll
    for (int k = 0; k < IN_F / 4 / 256; ++k)
        ((float4*)row)[t + k * 256] = z;
    __syncthreads();
    int cnt = counts[r * CSTR];
    if (cnt > CAP) cnt = CAP;
    const unsigned* bucket = pairs + (size_t)r * CAP;
    for (int j = t; j < cnt; j += 256) {
        unsigned p = bucket[j];
        atomicAdd(&row[p & 0xFFFu], __uint_as_float(p & 0xFFFF0000u));
    }
    __syncthreads();
    unsigned* dst = (unsigned*)(Wb + (size_t)r * IN_F);
#pragma unroll
    for (int k = 0; k < (IN_F / 2) / 256; ++k) {
        int ui = t + k * 256;
        unsigned lo = bf16_bits(row[ui * 2]);
        unsigned hi = bf16_bits(row[ui * 2 + 1]);
        dst[ui] = lo | (hi << 16);
    }
}

// ---------------- 3) GEMM: part[ksp] = x_bf16 @ W^T (slice), bf16-packed partials ----------------
// 256^2 tile, 8 waves (2M x 4N, 128x64 out each), KSPLIT=8, XCD-paired mapping (R14).
// NEW vs R14: BKT 64->32 gives 4 x 32KB LDS buffers in the same 128 KB -> prefetch
// depth 3 tiles (12 loads/thread in flight, counted vmcnt(12)); NKTH=16. Covers the
// ~900cy+queueing cold-W latency that one-tile lookahead (R14) left exposed.
// 64-B rows use chunk-rotation swizzle c' = (c + (row>>1)) & 3: staging stays in the
// row's 64-B window (coalesced) and frag reads are 2-way max (free per m136).
#define BM  256
#define BN  256
#define BKT 32
#define KSPLIT 8
#define KH   (IN_F / KSPLIT)            // 512
#define NKTH (KH / BKT)                 // 16
#define NWG  ((BATCH / BM) * (OUT_F / BN) * KSPLIT)   // 256

__global__ __launch_bounds__(512, 1) void gemm_part_kernel(
    const __hip_bfloat16* __restrict__ xb,   // (512, 4096) row-major
    const __hip_bfloat16* __restrict__ Wb,   // (4096, 4096) = (N, K) row-major
    unsigned* __restrict__ parts) {          // KSPLIT x (256, 4096) uint (2 bf16 rows each)

    __shared__ __align__(16) __hip_bfloat16 As[4][BM][BKT];   // 4 x 16 KB
    __shared__ __align__(16) __hip_bfloat16 Bs[4][BN][BKT];   // 4 x 16 KB

    // XCD-paired decomposition (xcd heuristic: bid % 8)
    const int xcd = blockIdx.x & 7;
    const int r   = blockIdx.x >> 3;          // 0..31
    const int bn0 = (2 * xcd + (r & 1)) * BN; // n tile 0..15
    const int bm0 = ((r >> 1) & 1) * BM;      // m tile 0..1
    const int ksp = r >> 2;                   // 0..7
    const size_t k0 = (size_t)ksp * KH;

    const int t  = threadIdx.x;               // 0..511
    const int l  = t & 63;
    const int w  = t >> 6;                    // wave 0..7
    const int wr = w >> 2;                    // M-half 0..1 (128 rows)
    const int wc = w & 3;                     // N-quarter 0..3 (64 cols)
    const int lr = l & 15;                    // frag lane
    const int lg = l >> 4;                    // k-group 0..3

    f32x4 acc[8][4] = {};

    // stage K-tile kt into buffer kt&3: A 1024 16B-chunks + B 1024 (2+2 gload_lds/thread).
    // chunk q: row=q>>2, dest chunk c'=q&3 holds global chunk (c' - (row>>1))&3, so the
    // frag read at c' = (lg + (row>>1))&3 retrieves k-chunk lg. Source stays within the
    // row's 64-B window -> coalesced; linear LDS dest satisfies global_load_lds.
#define STAGE(kt) do {                                                                            \
    const int _b = (kt) & 3;                                                                      \
    _Pragma("unroll")                                                                             \
    for (int j = 0; j < 2; ++j) {                                                                 \
        int q = t + j * 512; int row = q >> 2; int c = ((q & 3) - (row >> 1)) & 3;                \
        __builtin_amdgcn_global_load_lds(                                                         \
            (const unsigned*)(xb + (size_t)(bm0 + row) * IN_F + k0 + (kt) * BKT + c * 8),         \
            (unsigned*)((__hip_bfloat16*)As[_b] + q * 8), 16, 0, 0);                              \
    }                                                                                             \
    _Pragma("unroll")                                                                             \
    for (int j = 0; j < 2; ++j) {                                                                 \
        int q = t + j * 512; int row = q >> 2; int c = ((q & 3) - (row >> 1)) & 3;                \
        __builtin_amdgcn_global_load_lds(                                                         \
            (const unsigned*)(Wb + (size_t)(bn0 + row) * IN_F + k0 + (kt) * BKT + c * 8),         \
            (unsigned*)((__hip_bfloat16*)Bs[_b] + q * 8), 16, 0, 0);                              \
    }                                                                                             \
} while (0)

    const int rowA0 = wr * 128 + lr;          // +16i ; ((rowA0+16i)>>1)&3 == (rowA0>>1)&3
    const int rowB0 = wc * 64 + lr;
    const int cA = ((lg + (rowA0 >> 1)) & 3) * 8;   // uniform over i (16i>>1 = 8i ≡ 0 mod 4)
    const int cB = ((lg + (rowB0 >> 1)) & 3) * 8;

    STAGE(0); STAGE(1); STAGE(2);             // depth-3 prologue: 12 loads/thread in flight
    for (int kt = 0; kt < NKTH; ++kt) {
        const int b = kt & 3;
        if (kt + 3 < NKTH) {
            STAGE(kt + 3);                                     // refill to 16 outstanding
            asm volatile("s_waitcnt vmcnt(12)" ::: "memory");  // tile kt's 4 landed
        } else if (kt + 2 < NKTH) {
            asm volatile("s_waitcnt vmcnt(8)" ::: "memory");   // drain tail
        } else if (kt + 1 < NKTH) {
            asm volatile("s_waitcnt vmcnt(4)" ::: "memory");
        } else {
            asm volatile("s_waitcnt vmcnt(0)" ::: "memory");
        }
        __builtin_amdgcn_s_barrier();                          // all waves: tile kt ready

        bf16x8 a[8], b4[4];
#pragma unroll
        for (int i = 0; i < 8; ++i)
            a[i] = *(const bf16x8*)&As[b][rowA0 + 16 * i][cA];
#pragma unroll
        for (int i = 0; i < 4; ++i)
            b4[i] = *(const bf16x8*)&Bs[b][rowB0 + 16 * i][cB];
#pragma unroll
        for (int i = 0; i < 8; ++i)
#pragma unroll
            for (int j = 0; j < 4; ++j)
                acc[i][j] = __builtin_amdgcn_mfma_f32_16x16x32_bf16(a[i], b4[j], acc[i][j], 0, 0, 0);

        __builtin_amdgcn_s_barrier();   // all waves done with buffer b; restage at kt+1 is safe
    }

    // epilogue: pack row-pairs (rows 2r, 2r+1) as 2xbf16 in one uint; stream (no atomics).
    // C/D map: col=lane&15, row=(lane>>4)*4+reg -> row0 even, rg pairs {0,1},{2,3}.
    unsigned* pout = parts + (size_t)ksp * (BATCH / 2) * OUT_F;
    const int col  = bn0 + wc * 64 + lr;
    const int row0 = bm0 + wr * 128 + lg * 4;
#pragma unroll
    for (int i = 0; i < 8; ++i) {
        const int rp = (row0 + i * 16) >> 1;    // row-pair index
#pragma unroll
        for (int j = 0; j < 4; ++j) {
            unsigned u0 = bf16_bits(acc[i][j][0]) | (bf16_bits(acc[i][j][1]) << 16);
            unsigned u1 = bf16_bits(acc[i][j][2]) | (bf16_bits(acc[i][j][3]) << 16);
            pout[(size_t)rp * OUT_F + col + j * 16]       = u0;
            pout[(size_t)(rp + 1) * OUT_F + col + j * 16] = u1;
        }
    }
#undef STAGE
}

// ---------------- 4) reduce bf16-packed partials + bias -> out ----------------
__global__ void reduce_bias_kernel(const unsigned* __restrict__ parts,
                                   const float* __restrict__ bias,
                                   float* __restrict__ out) {
    const int NPQ = (BATCH / 2) * (OUT_F / 4);        // uint4 elements per slice
    int i = blockIdx.x * blockDim.x + threadIdx.x;
    if (i >= NPQ) return;
    float se[4] = {0.f, 0.f, 0.f, 0.f};               // even row (2rp)
    float so[4] = {0.f, 0.f, 0.f, 0.f};               // odd row (2rp+1)
#pragma unroll
    for (int k = 0; k < KSPLIT; ++k) {
        uint4 v = ((const uint4*)parts)[(size_t)k * NPQ + i];
        se[0] += bf16_val(v.x & 0xFFFFu); so[0] += bf16_val(v.x >> 16);
        se[1] += bf16_val(v.y & 0xFFFFu); so[1] += bf16_val(v.y >> 16);
        se[2] += bf16_val(v.z & 0xFFFFu); so[2] += bf16_val(v.z >> 16);
        se[3] += bf16_val(v.w & 0xFFFFu); so[3] += bf16_val(v.w >> 16);
    }
    const int cq = i & (OUT_F / 4 - 1);               // col/4
    const int rp = i / (OUT_F / 4);                   // row pair
    float4 bv = ((const float4*)bias)[cq];
    float4 oe = make_float4(se[0] + bv.x, se[1] + bv.y, se[2] + bv.z, se[3] + bv.w);
    float4 oo = make_float4(so[0] + bv.x, so[1] + bv.y, so[2] + bv.z, so[3] + bv.w);
    ((float4*)out)[(size_t)(2 * rp) * (OUT_F / 4) + cq]     = oe;
    ((float4*)out)[(size_t)(2 * rp + 1) * (OUT_F / 4) + cq] = oo;
}

extern "C" void kernel_launch(void* const* d_in, const int* in_sizes, int n_in,
                              void* d_out, int out_size, void* d_ws, size_t ws_size,
                              hipStream_t stream) {
    const float* x    = (const float*)d_in[0];   // (512, 4096) f32
    const float* wv   = (const float*)d_in[1];   // (nnz,) f32
    const float* bias = (const float*)d_in[2];   // (4096,) f32
    const int*   idx  = (const int*)d_in[3];     // (2, nnz) int32: rows then cols
    const int nnz = in_sizes[1];
    const int* rows = idx;
    const int* cols = idx + nnz;
    float* out = (float*)d_out;

    // workspace layout (16 B aligned chunks)
    char* ws = (char*)d_ws;
    __hip_bfloat16* Wb = (__hip_bfloat16*)ws; ws += (size_t)OUT_F * IN_F * sizeof(__hip_bfloat16); // 32 MB
    __hip_bfloat16* xb = (__hip_bfloat16*)ws; ws += (size_t)BATCH * IN_F * sizeof(__hip_bfloat16); // 4 MB
    int* counts = (int*)ws;                   ws += (size_t)OUT_F * CSTR * sizeof(int);            // 256 KB
    unsigned* pairs = (unsigned*)ws;          ws += (size_t)OUT_F * CAP * sizeof(unsigned) + 256;  // ~3.4 MB
    unsigned* parts = (unsigned*)ws;          // KSPLIT * (BATCH/2) * OUT_F * 4 B = 32 MB

    // 0) x->bf16 + counts<-0
    const int NTOT = BATCH * IN_F / 4 + OUT_F;
    convert_cnt_kernel<<<(NTOT + 255) / 256, 256, 0, stream>>>(x, xb, counts);

    // 1) bucket entries by row (packed 4 B: bf16 weight | col); padded counters
    int nthreads = (nnz + 3) / 4;
    int nb = (nthreads + 255) / 256;
    scatter_pairs_kernel<<<nb, 256, 0, stream>>>(rows, cols, wv, nnz, counts, pairs);

    // 2) densify W (sums duplicates via LDS atomics; writes zeros everywhere else)
    densify_rows_kernel<<<OUT_F, 256, 0, stream>>>(pairs, counts, Wb);

    // 3) dense MFMA GEMM, 256^2 tile, K-split=8, depth-3 prefetch, bf16 partials
    gemm_part_kernel<<<NWG, 512, 0, stream>>>(xb, Wb, parts);

    // 4) sum partials + bias -> out
    const int NPQ = (BATCH / 2) * (OUT_F / 4);
    reduce_bias_kernel<<<(NPQ + 255) / 256, 256, 0, stream>>>(parts, bias, out);
}